// Round 4
// baseline (297.258 us; speedup 1.0000x reference)
//
#include <hip/hip_runtime.h>
#include <hip/hip_bf16.h>
#include <math.h>

#define HPIX 128
#define WPIX 128
#define NPIX (HPIX*WPIX)   // 16384
#define CCH 64
#define P2 256             // number of windows (16x16)
#define HWIN 64            // pixels per window (8x8)

__device__ __forceinline__ float waveReduceSum(float v){
  #pragma unroll
  for (int m = 32; m >= 1; m >>= 1) v += __shfl_xor(v, m);
  return v;
}

// K1: x1(NHWC,f32) = x + dwconv3x3(x,pos_w,pos_b), from NCHW input.
__global__ void k1_posconv(const float* __restrict__ x, const float* __restrict__ pw,
                           const float* __restrict__ pb, float* __restrict__ x1){
  int tid = threadIdx.x;
  int pl = tid & 63;
  int cl = tid >> 6;
  int pix0 = (blockIdx.x & 255) * 64;
  int cg   = (blockIdx.x >> 8);
  int c = cg*4 + cl;
  int pix = pix0 + pl;
  int y = pix >> 7, xx = pix & 127;
  const float* xc = x + c*NPIX;
  float acc = pb[c];
  #pragma unroll
  for (int dy=0; dy<3; dy++){
    int yy = y+dy-1; if ((unsigned)yy >= (unsigned)HPIX) continue;
    #pragma unroll
    for (int dx=0; dx<3; dx++){
      int x2 = xx+dx-1; if ((unsigned)x2 >= (unsigned)WPIX) continue;
      acc += pw[c*9 + dy*3 + dx] * xc[yy*WPIX + x2];
    }
  }
  __shared__ float lds[4][64];
  lds[cl][pl] = xc[pix] + acc;
  __syncthreads();
  int pp = tid >> 2, cc = tid & 3;
  x1[(pix0+pp)*CCH + cg*4 + cc] = lds[cc][pp];
}

// K2: LN + qkv. 8 pixels/block, grid 2048 (8 blocks/CU -> high occupancy).
// lane = (pl 0-7, ch 0-7); thread computes 6 output cols.
__global__ void k2_ln_qkv(const float* __restrict__ x1,
                          const float* __restrict__ g, const float* __restrict__ bb,
                          const float* __restrict__ qw, const float* __restrict__ qb,
                          float* __restrict__ qkv){
  __shared__ float lnT[64][9];   // [ch][pix_local]
  int tid = threadIdx.x, w = tid >> 6, lane = tid & 63;
  int pix0 = blockIdx.x * 8;
  #pragma unroll
  for (int i=0; i<2; i++){
    int pl = w*2 + i, pix = pix0 + pl;
    float v = x1[pix*CCH + lane];
    float mean = waveReduceSum(v) * (1.f/64.f);
    float d = v - mean;
    float var = waveReduceSum(d*d) * (1.f/64.f);
    lnT[lane][pl] = d * rsqrtf(var + 1e-6f) * g[lane] + bb[lane];
  }
  __syncthreads();
  int pl = lane & 7, ch = lane >> 3;
  int co0 = w*48 + ch*6;
  float acc[6];
  #pragma unroll
  for (int j=0; j<6; j++) acc[j] = qb[co0+j];
  #pragma unroll 4
  for (int k=0; k<64; k++){
    float a = lnT[k][pl];
    const float* wr = qw + k*192 + co0;
    float2 u0 = *(const float2*)(wr);
    float2 u1 = *(const float2*)(wr + 2);
    float2 u2 = *(const float2*)(wr + 4);
    acc[0]+=a*u0.x; acc[1]+=a*u0.y; acc[2]+=a*u1.x;
    acc[3]+=a*u1.y; acc[4]+=a*u2.x; acc[5]+=a*u2.y;
  }
  int pix = pix0 + pl;
  int y = pix >> 7, xx = pix & 127;
  int p = (y>>3)*16 + (xx>>3);
  int r = ((y&7)<<3) + (xx&7);
  float* o = qkv + (p*HWIN + r)*192 + co0;
  *(float2*)(o)     = make_float2(acc[0], acc[1]);
  *(float2*)(o + 2) = make_float2(acc[2], acc[3]);
  *(float2*)(o + 4) = make_float2(acc[4], acc[5]);
}

// K3: per-window means; kwin stored TRANSPOSED [c][p] for k4 coalescing.
__global__ void k3_winmean(const float* __restrict__ qkv,
                           float* __restrict__ qwin, float* __restrict__ kwinT){
  int p = blockIdx.x;
  int tid = threadIdx.x, rq = tid >> 6, c = tid & 63;
  float sq = 0.f, sk = 0.f;
  for (int r = rq*16; r < rq*16+16; r++){
    const float* row = qkv + (p*HWIN + r)*192;
    sq += row[c];
    sk += row[64 + c];
  }
  __shared__ float s1[4][64], s2[4][64];
  s1[rq][c] = sq; s2[rq][c] = sk;
  __syncthreads();
  if (tid < 64){
    qwin[p*64 + c]   = (s1[0][c]+s1[1][c]+s1[2][c]+s1[3][c])*(1.f/64.f);
    kwinT[c*P2 + p]  = (s2[0][c]+s2[1][c]+s2[2][c]+s2[3][c])*(1.f/64.f);
  }
}

// K4: logits + top-4 (desc, ties -> lowest index). kwinT reads coalesced.
__global__ void k4_topk(const float* __restrict__ qwin, const float* __restrict__ kwinT,
                        int* __restrict__ idx){
  int p = blockIdx.x, t = threadIdx.x;
  int w = t >> 6, lane = t & 63;
  __shared__ float qs[64];
  __shared__ float lg[P2];
  __shared__ float wv[4]; __shared__ int wi[4];
  if (t < 64) qs[t] = qwin[p*64 + t];
  __syncthreads();
  float acc = 0.f;
  #pragma unroll 8
  for (int c=0; c<64; c++) acc += qs[c] * kwinT[c*P2 + t];
  lg[t] = acc;
  __syncthreads();
  for (int j=0; j<4; j++){
    float v = lg[t]; int i = t;
    #pragma unroll
    for (int m=32; m>=1; m>>=1){
      float ov = __shfl_xor(v, m); int oi = __shfl_xor(i, m);
      if (ov > v || (ov == v && oi < i)){ v = ov; i = oi; }
    }
    if (lane == 0){ wv[w] = v; wi[w] = i; }
    __syncthreads();
    if (t == 0){
      float bv = wv[0]; int bi = wi[0];
      #pragma unroll
      for (int u=1; u<4; u++)
        if (wv[u] > bv || (wv[u] == bv && wi[u] < bi)){ bv = wv[u]; bi = wi[u]; }
      idx[p*4 + j] = bi;
      lg[bi] = -1e30f;
    }
    __syncthreads();
  }
}

// K5: attention for (window p, head n). 4 waves split 256 keys.
// Logits are tiny (|s| << 10): plain exp(s), no online-max chain -> partial
// sums merge as straight sums. grid 2048, block 256.
__global__ void k5_attn(const float* __restrict__ qkv, const int* __restrict__ idx,
                        float* __restrict__ attnout){
  int p = blockIdx.x >> 3, n = blockIdx.x & 7;
  int tid = threadIdx.x, w = tid >> 6, lane = tid & 63;
  __shared__ float Ks[256][8];
  __shared__ float Vs[256][8];
  __shared__ int wsel[4];
  __shared__ float ps[4][64][9];
  if (tid < 4) wsel[tid] = idx[p*4 + tid];
  __syncthreads();
  int cb = n*8;
  for (int u = tid; u < 512; u += 256){
    int k = u >> 1, h = u & 1;
    const float* row = qkv + (wsel[k>>6]*HWIN + (k&63))*192;
    *(float4*)&Ks[k][h*4] = *(const float4*)(row + 64  + cb + h*4);
    *(float4*)&Vs[k][h*4] = *(const float4*)(row + 128 + cb + h*4);
  }
  __syncthreads();
  const float* qrow = qkv + (p*HWIN + lane)*192 + cb;
  float q[8];
  #pragma unroll
  for (int d=0; d<8; d++) q[d] = qrow[d] * 0.125f;
  float l = 0.f, acc[8];
  #pragma unroll
  for (int d=0; d<8; d++) acc[d] = 0.f;
  #pragma unroll 4
  for (int k = w*64; k < w*64+64; k++){
    float4 ka = *(float4*)&Ks[k][0];
    float4 kb = *(float4*)&Ks[k][4];
    float s = q[0]*ka.x + q[1]*ka.y + q[2]*ka.z + q[3]*ka.w
            + q[4]*kb.x + q[5]*kb.y + q[6]*kb.z + q[7]*kb.w;
    float e = __expf(s);
    l += e;
    float4 va = *(float4*)&Vs[k][0];
    float4 vb = *(float4*)&Vs[k][4];
    acc[0]+=e*va.x; acc[1]+=e*va.y; acc[2]+=e*va.z; acc[3]+=e*va.w;
    acc[4]+=e*vb.x; acc[5]+=e*vb.y; acc[6]+=e*vb.z; acc[7]+=e*vb.w;
  }
  ps[w][lane][8] = l;
  #pragma unroll
  for (int d=0; d<8; d++) ps[w][lane][d] = acc[d];
  __syncthreads();
  if (w == 0){
    float L = 0.f, o[8];
    #pragma unroll
    for (int d=0; d<8; d++) o[d] = 0.f;
    #pragma unroll
    for (int u=0; u<4; u++){
      L += ps[u][lane][8];
      #pragma unroll
      for (int d=0; d<8; d++) o[d] += ps[u][lane][d];
    }
    float inv = 1.f / L;
    int yy = (p>>4)*8 + (lane>>3), xx = (p&15)*8 + (lane&7);
    float* orow = attnout + (yy*WPIX + xx)*CCH + cb;
    #pragma unroll
    for (int d=0; d<8; d++) orow[d] = o[d]*inv;
  }
}

// K6: t = attnout + lepe5x5(v); x1 += t @ wo_w + wo_b. 8 pixels/block, grid 2048.
__global__ void k6_lepe_wo(const float* __restrict__ attnout, const float* __restrict__ qkv,
                           const float* __restrict__ lw, const float* __restrict__ lb,
                           const float* __restrict__ ww, const float* __restrict__ wb,
                           float* __restrict__ x1){
  __shared__ float tT[64][9];   // [ch][pix_local]
  int tid = threadIdx.x, w = tid >> 6, lane = tid & 63;
  int pix0 = blockIdx.x * 8;
  #pragma unroll
  for (int i=0; i<2; i++){
    int pl = w*2 + i, pix = pix0 + pl;
    int y = pix >> 7, xx = pix & 127;
    float acc = lb[lane];
    #pragma unroll
    for (int dy=0; dy<5; dy++){
      int yy = y+dy-2; if ((unsigned)yy >= (unsigned)HPIX) continue;
      #pragma unroll
      for (int dx=0; dx<5; dx++){
        int x2 = xx+dx-2; if ((unsigned)x2 >= (unsigned)WPIX) continue;
        int pp = (yy>>3)*16 + (x2>>3), rr = ((yy&7)<<3) + (x2&7);
        acc += lw[lane*25 + dy*5 + dx] * qkv[(pp*HWIN + rr)*192 + 128 + lane];
      }
    }
    tT[lane][pl] = attnout[pix*CCH + lane] + acc;
  }
  __syncthreads();
  int pl = lane & 7, ch = lane >> 3;
  int j0 = w*16 + ch*2;
  float a0 = wb[j0], a1 = wb[j0+1];
  #pragma unroll 8
  for (int k=0; k<64; k++){
    float a = tT[k][pl];
    float2 u = *(const float2*)(ww + k*64 + j0);
    a0 += a*u.x; a1 += a*u.y;
  }
  int pix = pix0 + pl;
  float* xb = x1 + pix*CCH + j0;
  float2 r = *(float2*)xb;
  r.x += a0; r.y += a1;
  *(float2*)xb = r;
}

// K7: y=LN(x2); h=gelu(y@w1+b1); o=h@w2+b2; out(NCHW)=x2+o.
// 8 pixels/block, grid 2048; LDS 13.5 KB -> 8+ blocks/CU.
__global__ void k7_mlp_out(const float* __restrict__ x2,
                           const float* __restrict__ g, const float* __restrict__ bb,
                           const float* __restrict__ w1, const float* __restrict__ b1,
                           const float* __restrict__ w2, const float* __restrict__ b2,
                           float* __restrict__ out){
  __shared__ float lnT[64][9];
  __shared__ float x2T[64][9];
  __shared__ float hidT[256][9];
  int tid = threadIdx.x, w = tid >> 6, lane = tid & 63;
  int pix0 = blockIdx.x * 8;
  #pragma unroll
  for (int i=0; i<2; i++){
    int pl = w*2 + i, pix = pix0 + pl;
    float v = x2[pix*CCH + lane];
    float mean = waveReduceSum(v) * (1.f/64.f);
    float d = v - mean;
    float var = waveReduceSum(d*d) * (1.f/64.f);
    x2T[lane][pl] = v;
    lnT[lane][pl] = d * rsqrtf(var + 1e-6f) * g[lane] + bb[lane];
  }
  __syncthreads();
  int pl = lane & 7, ch = lane >> 3;
  {
    int co0 = w*64 + ch*8;
    float acc[8];
    #pragma unroll
    for (int j=0; j<8; j++) acc[j] = b1[co0+j];
    #pragma unroll 4
    for (int k=0; k<64; k++){
      float a = lnT[k][pl];
      const float* wr = w1 + k*256 + co0;
      float4 u0 = *(const float4*)(wr);
      float4 u1 = *(const float4*)(wr + 4);
      acc[0]+=a*u0.x; acc[1]+=a*u0.y; acc[2]+=a*u0.z; acc[3]+=a*u0.w;
      acc[4]+=a*u1.x; acc[5]+=a*u1.y; acc[6]+=a*u1.z; acc[7]+=a*u1.w;
    }
    #pragma unroll
    for (int j=0; j<8; j++){
      float h = acc[j];
      h = 0.5f*h*(1.f + erff(h*0.70710678118654752f));
      hidT[co0+j][pl] = h;
    }
  }
  __syncthreads();
  {
    int j0 = w*16 + ch*2;
    float a0 = b2[j0], a1 = b2[j0+1];
    #pragma unroll 8
    for (int k=0; k<256; k++){
      float a = hidT[k][pl];
      float2 u = *(const float2*)(w2 + k*64 + j0);
      a0 += a*u.x; a1 += a*u.y;
    }
    int pix = pix0 + pl;
    out[j0*NPIX + pix]     = x2T[j0][pl]   + a0;
    out[(j0+1)*NPIX + pix] = x2T[j0+1][pl] + a1;
  }
}

extern "C" void kernel_launch(void* const* d_in, const int* in_sizes, int n_in,
                              void* d_out, int out_size, void* d_ws, size_t ws_size,
                              hipStream_t stream) {
  (void)in_sizes; (void)n_in; (void)out_size; (void)ws_size;
  const float* x      = (const float*)d_in[0];
  const float* pos_w  = (const float*)d_in[1];
  const float* pos_b  = (const float*)d_in[2];
  const float* norm_g = (const float*)d_in[3];
  const float* norm_b = (const float*)d_in[4];
  const float* qkv_w  = (const float*)d_in[5];
  const float* qkv_b  = (const float*)d_in[6];
  const float* wo_w   = (const float*)d_in[7];
  const float* wo_b   = (const float*)d_in[8];
  const float* lepe_w = (const float*)d_in[9];
  const float* lepe_b = (const float*)d_in[10];
  const float* mlp_w1 = (const float*)d_in[11];
  const float* mlp_b1 = (const float*)d_in[12];
  const float* mlp_w2 = (const float*)d_in[13];
  const float* mlp_b2 = (const float*)d_in[14];
  float* out = (float*)d_out;

  char* ws = (char*)d_ws;
  float* x1      = (float*)(ws);                          // 4 MB  (becomes x2)
  float* qkv     = (float*)(ws + (4u<<20));               // 12 MB [p][r][192]
  float* qwin    = (float*)(ws + (16u<<20));              // 64 KB
  float* kwinT   = (float*)(ws + (16u<<20) + (64u<<10));  // 64 KB  [c][p]
  int*   idx     = (int*)  (ws + (16u<<20) + (128u<<10)); // 4 KB
  float* attnout = (float*)(ws + (17u<<20));              // 4 MB (NHWC)

  hipLaunchKernelGGL(k1_posconv, dim3(4096), dim3(256), 0, stream, x, pos_w, pos_b, x1);
  hipLaunchKernelGGL(k2_ln_qkv,  dim3(2048), dim3(256), 0, stream, x1, norm_g, norm_b, qkv_w, qkv_b, qkv);
  hipLaunchKernelGGL(k3_winmean, dim3(256),  dim3(256), 0, stream, qkv, qwin, kwinT);
  hipLaunchKernelGGL(k4_topk,    dim3(256),  dim3(256), 0, stream, qwin, kwinT, idx);
  hipLaunchKernelGGL(k5_attn,    dim3(2048), dim3(256), 0, stream, qkv, idx, attnout);
  hipLaunchKernelGGL(k6_lepe_wo, dim3(2048), dim3(256), 0, stream, attnout, qkv, lepe_w, lepe_b, wo_w, wo_b, x1);
  hipLaunchKernelGGL(k7_mlp_out, dim3(2048), dim3(256), 0, stream, x1, norm_g, norm_b, mlp_w1, mlp_b1, mlp_w2, mlp_b2, out);
}

// Round 5
// 213.300 us; speedup vs baseline: 1.3936x; 1.3936x over previous
//
#include <hip/hip_runtime.h>
#include <hip/hip_bf16.h>
#include <math.h>

#define HPIX 128
#define WPIX 128
#define NPIX (HPIX*WPIX)   // 16384
#define CCH 64
#define P2 256             // number of windows (16x16)
#define HWIN 64            // pixels per window (8x8)
#define LNS 36             // LDS row stride (floats): 144B, 16B-aligned

__device__ __forceinline__ float waveReduceSum(float v){
  #pragma unroll
  for (int m = 32; m >= 1; m >>= 1) v += __shfl_xor(v, m);
  return v;
}

__device__ __forceinline__ float gelu_exact(float h){
  return 0.5f*h*(1.f + erff(h*0.70710678118654752f));
}

// K1: x1(NHWC,f32) = x + dwconv3x3(x,pos_w,pos_b), from NCHW input.
__global__ void k1_posconv(const float* __restrict__ x, const float* __restrict__ pw,
                           const float* __restrict__ pb, float* __restrict__ x1){
  int tid = threadIdx.x;
  int pl = tid & 63;
  int cl = tid >> 6;
  int pix0 = (blockIdx.x & 255) * 64;
  int cg   = (blockIdx.x >> 8);
  int c = cg*4 + cl;
  int pix = pix0 + pl;
  int y = pix >> 7, xx = pix & 127;
  const float* xc = x + c*NPIX;
  float acc = pb[c];
  #pragma unroll
  for (int dy=0; dy<3; dy++){
    int yy = y+dy-1; if ((unsigned)yy >= (unsigned)HPIX) continue;
    #pragma unroll
    for (int dx=0; dx<3; dx++){
      int x2 = xx+dx-1; if ((unsigned)x2 >= (unsigned)WPIX) continue;
      acc += pw[c*9 + dy*3 + dx] * xc[yy*WPIX + x2];
    }
  }
  __shared__ float lds[4][64];
  lds[cl][pl] = xc[pix] + acc;
  __syncthreads();
  int pp = tid >> 2, cc = tid & 3;
  x1[(pix0+pp)*CCH + cg*4 + cc] = lds[cc][pp];
}

// K2: LN + qkv, register-tiled. 32 pixels/block, grid 512.
// Thread tile: 4 pixels x 6 output cols; per-k: ds_read_b128 + 24B weights -> 24 FMA.
__global__ void k2_ln_qkv(const float* __restrict__ x1,
                          const float* __restrict__ g, const float* __restrict__ bb,
                          const float* __restrict__ qw, const float* __restrict__ qb,
                          float* __restrict__ qkv){
  __shared__ float lnT[64][LNS];   // [ch][pix_local]
  int tid = threadIdx.x, w = tid >> 6, lane = tid & 63;
  int pix0 = blockIdx.x * 32;
  #pragma unroll
  for (int i=0; i<8; i++){
    int pl = w*8 + i, pix = pix0 + pl;
    float v = x1[pix*CCH + lane];
    float mean = waveReduceSum(v) * (1.f/64.f);
    float d = v - mean;
    float var = waveReduceSum(d*d) * (1.f/64.f);
    lnT[lane][pl] = d * rsqrtf(var + 1e-6f) * g[lane] + bb[lane];
  }
  __syncthreads();
  int p0 = (tid & 7) * 4;       // 4 pixels
  int cg = tid >> 3;            // 0..31 -> 6 cols each
  int j0 = cg * 6;
  float acc[4][6];
  #pragma unroll
  for (int i=0;i<4;i++)
    #pragma unroll
    for (int j=0;j<6;j++) acc[i][j] = qb[j0+j];
  #pragma unroll 4
  for (int k=0; k<64; k++){
    float4 a = *(const float4*)&lnT[k][p0];
    const float* wr = qw + k*192 + j0;
    float2 u0 = *(const float2*)(wr);
    float2 u1 = *(const float2*)(wr+2);
    float2 u2 = *(const float2*)(wr+4);
    float av[4] = {a.x, a.y, a.z, a.w};
    #pragma unroll
    for (int i=0;i<4;i++){
      acc[i][0] += av[i]*u0.x; acc[i][1] += av[i]*u0.y;
      acc[i][2] += av[i]*u1.x; acc[i][3] += av[i]*u1.y;
      acc[i][4] += av[i]*u2.x; acc[i][5] += av[i]*u2.y;
    }
  }
  int y = pix0 >> 7;
  #pragma unroll
  for (int i=0;i<4;i++){
    int pix = pix0 + p0 + i;
    int xx = pix & 127;
    int p = (y>>3)*16 + (xx>>3);
    int r = ((y&7)<<3) + (xx&7);
    float* o = qkv + (p*HWIN + r)*192 + j0;
    *(float2*)(o)     = make_float2(acc[i][0], acc[i][1]);
    *(float2*)(o + 2) = make_float2(acc[i][2], acc[i][3]);
    *(float2*)(o + 4) = make_float2(acc[i][4], acc[i][5]);
  }
}

// K3: per-window means; kwin stored TRANSPOSED [c][p] for k4 coalescing.
__global__ void k3_winmean(const float* __restrict__ qkv,
                           float* __restrict__ qwin, float* __restrict__ kwinT){
  int p = blockIdx.x;
  int tid = threadIdx.x, rq = tid >> 6, c = tid & 63;
  float sq = 0.f, sk = 0.f;
  for (int r = rq*16; r < rq*16+16; r++){
    const float* row = qkv + (p*HWIN + r)*192;
    sq += row[c];
    sk += row[64 + c];
  }
  __shared__ float s1[4][64], s2[4][64];
  s1[rq][c] = sq; s2[rq][c] = sk;
  __syncthreads();
  if (tid < 64){
    qwin[p*64 + c]   = (s1[0][c]+s1[1][c]+s1[2][c]+s1[3][c])*(1.f/64.f);
    kwinT[c*P2 + p]  = (s2[0][c]+s2[1][c]+s2[2][c]+s2[3][c])*(1.f/64.f);
  }
}

// K4: logits + top-4 (desc, ties -> lowest index). kwinT reads coalesced.
__global__ void k4_topk(const float* __restrict__ qwin, const float* __restrict__ kwinT,
                        int* __restrict__ idx){
  int p = blockIdx.x, t = threadIdx.x;
  int w = t >> 6, lane = t & 63;
  __shared__ float qs[64];
  __shared__ float lg[P2];
  __shared__ float wv[4]; __shared__ int wi[4];
  if (t < 64) qs[t] = qwin[p*64 + t];
  __syncthreads();
  float acc = 0.f;
  #pragma unroll 8
  for (int c=0; c<64; c++) acc += qs[c] * kwinT[c*P2 + t];
  lg[t] = acc;
  __syncthreads();
  for (int j=0; j<4; j++){
    float v = lg[t]; int i = t;
    #pragma unroll
    for (int m=32; m>=1; m>>=1){
      float ov = __shfl_xor(v, m); int oi = __shfl_xor(i, m);
      if (ov > v || (ov == v && oi < i)){ v = ov; i = oi; }
    }
    if (lane == 0){ wv[w] = v; wi[w] = i; }
    __syncthreads();
    if (t == 0){
      float bv = wv[0]; int bi = wi[0];
      #pragma unroll
      for (int u=1; u<4; u++)
        if (wv[u] > bv || (wv[u] == bv && wi[u] < bi)){ bv = wv[u]; bi = wi[u]; }
      idx[p*4 + j] = bi;
      lg[bi] = -1e30f;
    }
    __syncthreads();
  }
}

// K5: attention for (window p, head n). 4 waves split 256 keys; plain exp
// (logits tiny), straight-sum merge. grid 2048, block 256.
__global__ void k5_attn(const float* __restrict__ qkv, const int* __restrict__ idx,
                        float* __restrict__ attnout){
  int p = blockIdx.x >> 3, n = blockIdx.x & 7;
  int tid = threadIdx.x, w = tid >> 6, lane = tid & 63;
  __shared__ float Ks[256][8];
  __shared__ float Vs[256][8];
  __shared__ int wsel[4];
  __shared__ float ps[4][64][9];
  if (tid < 4) wsel[tid] = idx[p*4 + tid];
  __syncthreads();
  int cb = n*8;
  for (int u = tid; u < 512; u += 256){
    int k = u >> 1, h = u & 1;
    const float* row = qkv + (wsel[k>>6]*HWIN + (k&63))*192;
    *(float4*)&Ks[k][h*4] = *(const float4*)(row + 64  + cb + h*4);
    *(float4*)&Vs[k][h*4] = *(const float4*)(row + 128 + cb + h*4);
  }
  __syncthreads();
  const float* qrow = qkv + (p*HWIN + lane)*192 + cb;
  float q[8];
  #pragma unroll
  for (int d=0; d<8; d++) q[d] = qrow[d] * 0.125f;
  float l = 0.f, acc[8];
  #pragma unroll
  for (int d=0; d<8; d++) acc[d] = 0.f;
  #pragma unroll 4
  for (int k = w*64; k < w*64+64; k++){
    float4 ka = *(float4*)&Ks[k][0];
    float4 kb = *(float4*)&Ks[k][4];
    float s = q[0]*ka.x + q[1]*ka.y + q[2]*ka.z + q[3]*ka.w
            + q[4]*kb.x + q[5]*kb.y + q[6]*kb.z + q[7]*kb.w;
    float e = __expf(s);
    l += e;
    float4 va = *(float4*)&Vs[k][0];
    float4 vb = *(float4*)&Vs[k][4];
    acc[0]+=e*va.x; acc[1]+=e*va.y; acc[2]+=e*va.z; acc[3]+=e*va.w;
    acc[4]+=e*vb.x; acc[5]+=e*vb.y; acc[6]+=e*vb.z; acc[7]+=e*vb.w;
  }
  ps[w][lane][8] = l;
  #pragma unroll
  for (int d=0; d<8; d++) ps[w][lane][d] = acc[d];
  __syncthreads();
  if (w == 0){
    float L = 0.f, o[8];
    #pragma unroll
    for (int d=0; d<8; d++) o[d] = 0.f;
    #pragma unroll
    for (int u=0; u<4; u++){
      L += ps[u][lane][8];
      #pragma unroll
      for (int d=0; d<8; d++) o[d] += ps[u][lane][d];
    }
    float inv = 1.f / L;
    int yy = (p>>4)*8 + (lane>>3), xx = (p&15)*8 + (lane&7);
    float* orow = attnout + (yy*WPIX + xx)*CCH + cb;
    #pragma unroll
    for (int d=0; d<8; d++) orow[d] = o[d]*inv;
  }
}

// K6: t = attnout + lepe5x5(v); x1 += t @ wo_w + wo_b. Register-tiled.
// 32 pixels/block, grid 512. Thread tile: 4 pixels x 2 cols.
__global__ void k6_lepe_wo(const float* __restrict__ attnout, const float* __restrict__ qkv,
                           const float* __restrict__ lw, const float* __restrict__ lb,
                           const float* __restrict__ ww, const float* __restrict__ wb,
                           float* __restrict__ x1){
  __shared__ float tT[64][LNS];   // [ch][pix_local]
  int tid = threadIdx.x, w = tid >> 6, lane = tid & 63;
  int pix0 = blockIdx.x * 32;
  for (int i=0; i<8; i++){
    int pl = w*8 + i, pix = pix0 + pl;
    int y = pix >> 7, xx = pix & 127;
    float acc = lb[lane];
    #pragma unroll
    for (int dy=0; dy<5; dy++){
      int yy = y+dy-2; if ((unsigned)yy >= (unsigned)HPIX) continue;
      #pragma unroll
      for (int dx=0; dx<5; dx++){
        int x2 = xx+dx-2; if ((unsigned)x2 >= (unsigned)WPIX) continue;
        int pp = (yy>>3)*16 + (x2>>3), rr = ((yy&7)<<3) + (x2&7);
        acc += lw[lane*25 + dy*5 + dx] * qkv[(pp*HWIN + rr)*192 + 128 + lane];
      }
    }
    tT[lane][pl] = attnout[pix*CCH + lane] + acc;
  }
  __syncthreads();
  int p0 = (tid & 7) * 4;
  int cg = tid >> 3;
  int j0 = cg * 2;
  float a0[4], a1[4];
  #pragma unroll
  for (int i=0;i<4;i++){ a0[i] = wb[j0]; a1[i] = wb[j0+1]; }
  #pragma unroll 4
  for (int k=0; k<64; k++){
    float4 a = *(const float4*)&tT[k][p0];
    float2 u = *(const float2*)(ww + k*64 + j0);
    a0[0]+=a.x*u.x; a1[0]+=a.x*u.y;
    a0[1]+=a.y*u.x; a1[1]+=a.y*u.y;
    a0[2]+=a.z*u.x; a1[2]+=a.z*u.y;
    a0[3]+=a.w*u.x; a1[3]+=a.w*u.y;
  }
  #pragma unroll
  for (int i=0;i<4;i++){
    int pix = pix0 + p0 + i;
    float* xb = x1 + pix*CCH + j0;
    float2 r = *(float2*)xb;
    r.x += a0[i]; r.y += a1[i];
    *(float2*)xb = r;
  }
}

// K7: y=LN(x2); h=gelu(y@w1+b1); o=h@w2+b2; out(NCHW)=x2+o. Register-tiled.
// 32 pixels/block, grid 512. fc1 tile: 4 pix x 8 cols (32 acc); fc2: 4 pix x 2 cols.
__global__ void k7_mlp_out(const float* __restrict__ x2,
                           const float* __restrict__ g, const float* __restrict__ bb,
                           const float* __restrict__ w1, const float* __restrict__ b1,
                           const float* __restrict__ w2, const float* __restrict__ b2,
                           float* __restrict__ out){
  __shared__ float lnT[64][LNS];
  __shared__ float hidT[256][LNS];
  int tid = threadIdx.x, w = tid >> 6, lane = tid & 63;
  int pix0 = blockIdx.x * 32;
  #pragma unroll
  for (int i=0; i<8; i++){
    int pl = w*8 + i, pix = pix0 + pl;
    float v = x2[pix*CCH + lane];
    float mean = waveReduceSum(v) * (1.f/64.f);
    float d = v - mean;
    float var = waveReduceSum(d*d) * (1.f/64.f);
    lnT[lane][pl] = d * rsqrtf(var + 1e-6f) * g[lane] + bb[lane];
  }
  __syncthreads();
  int p0 = (tid & 7) * 4;
  int cg = tid >> 3;            // 0..31
  {
    int j0 = cg * 8;            // 8 hidden cols
    float acc[4][8];
    #pragma unroll
    for (int i=0;i<4;i++)
      #pragma unroll
      for (int j=0;j<8;j++) acc[i][j] = b1[j0+j];
    #pragma unroll 2
    for (int k=0; k<64; k++){
      float4 a = *(const float4*)&lnT[k][p0];
      const float* wr = w1 + k*256 + j0;
      float4 u0 = *(const float4*)(wr);
      float4 u1 = *(const float4*)(wr + 4);
      float av[4] = {a.x, a.y, a.z, a.w};
      #pragma unroll
      for (int i=0;i<4;i++){
        acc[i][0]+=av[i]*u0.x; acc[i][1]+=av[i]*u0.y;
        acc[i][2]+=av[i]*u0.z; acc[i][3]+=av[i]*u0.w;
        acc[i][4]+=av[i]*u1.x; acc[i][5]+=av[i]*u1.y;
        acc[i][6]+=av[i]*u1.z; acc[i][7]+=av[i]*u1.w;
      }
    }
    #pragma unroll
    for (int j=0;j<8;j++){
      float4 hv;
      hv.x = gelu_exact(acc[0][j]);
      hv.y = gelu_exact(acc[1][j]);
      hv.z = gelu_exact(acc[2][j]);
      hv.w = gelu_exact(acc[3][j]);
      *(float4*)&hidT[j0+j][p0] = hv;
    }
  }
  __syncthreads();
  {
    int j0 = cg * 2;            // 2 output cols
    float a0[4], a1[4];
    #pragma unroll
    for (int i=0;i<4;i++){ a0[i] = b2[j0]; a1[i] = b2[j0+1]; }
    #pragma unroll 4
    for (int k=0; k<256; k++){
      float4 a = *(const float4*)&hidT[k][p0];
      float2 u = *(const float2*)(w2 + k*64 + j0);
      a0[0]+=a.x*u.x; a1[0]+=a.x*u.y;
      a0[1]+=a.y*u.x; a1[1]+=a.y*u.y;
      a0[2]+=a.z*u.x; a1[2]+=a.z*u.y;
      a0[3]+=a.w*u.x; a1[3]+=a.w*u.y;
    }
    float4 o0, o1;
    float* r0 = &o0.x; float* r1 = &o1.x;
    #pragma unroll
    for (int i=0;i<4;i++){
      int pix = pix0 + p0 + i;
      r0[i] = x2[pix*CCH + j0]     + a0[i];
      r1[i] = x2[pix*CCH + j0 + 1] + a1[i];
    }
    *(float4*)&out[j0*NPIX + pix0 + p0]     = o0;
    *(float4*)&out[(j0+1)*NPIX + pix0 + p0] = o1;
  }
}

extern "C" void kernel_launch(void* const* d_in, const int* in_sizes, int n_in,
                              void* d_out, int out_size, void* d_ws, size_t ws_size,
                              hipStream_t stream) {
  (void)in_sizes; (void)n_in; (void)out_size; (void)ws_size;
  const float* x      = (const float*)d_in[0];
  const float* pos_w  = (const float*)d_in[1];
  const float* pos_b  = (const float*)d_in[2];
  const float* norm_g = (const float*)d_in[3];
  const float* norm_b = (const float*)d_in[4];
  const float* qkv_w  = (const float*)d_in[5];
  const float* qkv_b  = (const float*)d_in[6];
  const float* wo_w   = (const float*)d_in[7];
  const float* wo_b   = (const float*)d_in[8];
  const float* lepe_w = (const float*)d_in[9];
  const float* lepe_b = (const float*)d_in[10];
  const float* mlp_w1 = (const float*)d_in[11];
  const float* mlp_b1 = (const float*)d_in[12];
  const float* mlp_w2 = (const float*)d_in[13];
  const float* mlp_b2 = (const float*)d_in[14];
  float* out = (float*)d_out;

  char* ws = (char*)d_ws;
  float* x1      = (float*)(ws);                          // 4 MB  (becomes x2)
  float* qkv     = (float*)(ws + (4u<<20));               // 12 MB [p][r][192]
  float* qwin    = (float*)(ws + (16u<<20));              // 64 KB
  float* kwinT   = (float*)(ws + (16u<<20) + (64u<<10));  // 64 KB  [c][p]
  int*   idx     = (int*)  (ws + (16u<<20) + (128u<<10)); // 4 KB
  float* attnout = (float*)(ws + (17u<<20));              // 4 MB (NHWC)

  hipLaunchKernelGGL(k1_posconv, dim3(4096), dim3(256), 0, stream, x, pos_w, pos_b, x1);
  hipLaunchKernelGGL(k2_ln_qkv,  dim3(512),  dim3(256), 0, stream, x1, norm_g, norm_b, qkv_w, qkv_b, qkv);
  hipLaunchKernelGGL(k3_winmean, dim3(256),  dim3(256), 0, stream, qkv, qwin, kwinT);
  hipLaunchKernelGGL(k4_topk,    dim3(256),  dim3(256), 0, stream, qwin, kwinT, idx);
  hipLaunchKernelGGL(k5_attn,    dim3(2048), dim3(256), 0, stream, qkv, idx, attnout);
  hipLaunchKernelGGL(k6_lepe_wo, dim3(512),  dim3(256), 0, stream, attnout, qkv, lepe_w, lepe_b, wo_w, wo_b, x1);
  hipLaunchKernelGGL(k7_mlp_out, dim3(512),  dim3(256), 0, stream, x1, norm_g, norm_b, mlp_w1, mlp_b1, mlp_w2, mlp_b2, out);
}